// Round 7
// baseline (518.719 us; speedup 1.0000x reference)
//
#include <hip/hip_runtime.h>
#include <math.h>

// Fused dual-LeNet + len-19 full convolution + log.
// 2 samples (4 LeNet instances) per block, 256 threads.
// Round-7 design: weights come from GLOBAL (L1-resident) via lane-fixed
// output channel (conv1: o=tid%6, conv2: o=tid%16) -> zero LDS weight
// traffic (R6: ~45% of LDS cycles were scalar weight reads).
// Rolling-row convolution keeps live state ~50 VGPRs (no spill).
// LDS 26.7 KB -> 6 blocks/CU.

#define SPB 2            // samples per block
#define P1_IC  148       // s_p1 channel stride (mod 32 = 20)
#define P1_IN  888       // s_p1 instance stride = 6*148 (mod 32 = 24)

__global__ __launch_bounds__(256) void lenet_fused(
    const float* __restrict__ x,     // [B,2,28,28]
    const float* __restrict__ cw1,   // [6,1,5,5]
    const float* __restrict__ cb1,   // [6]
    const float* __restrict__ cw2,   // [16,6,5,5]
    const float* __restrict__ cb2,   // [16]
    const float* __restrict__ fw1,   // [120,256]
    const float* __restrict__ fb1,   // [120]
    const float* __restrict__ fw2,   // [84,120]
    const float* __restrict__ fb2,   // [84]
    const float* __restrict__ fw3,   // [10,84]
    const float* __restrict__ fb3,   // [10]
    float* __restrict__ out)         // [B,19]
{
    const int tid = threadIdx.x;
    const int b0  = blockIdx.x * SPB;

    // s_pool: images (3136 fl) during conv1; then p2/f1/f2/log (1880 fl).
    __shared__ __align__(16) float s_pool[4 * 784];      // 12544 B
    __shared__ __align__(16) float s_p1  [4 * P1_IN];    // 14208 B
    // total 26752 B -> 6 blocks/CU

    float* s_img = s_pool;           // 3136 floats (4 inst x 784)
    float* s_p2  = s_pool;           // 1024
    float* s_f1  = s_pool + 1024;    // 480
    float* s_f2  = s_pool + 1504;    // 336
    float* s_log = s_pool + 1840;    // 40

    // ---- stage images: 784 float4, coalesced ----
    {
        const float4* xb = (const float4*)(x + (size_t)b0 * 1568);
        float4* si = (float4*)s_img;
        for (int i = tid; i < 784; i += 256) si[i] = xb[i];
    }
    __syncthreads();

    // ---- conv1 5x5 (1->6) + pool2x2 + relu ----
    // lane-fixed o = tid%6 (252 lanes); tasks per o: 144 = 4inst x 12py x 3g
    if (tid < 252) {
        const int o  = tid % 6;
        const int li = tid / 6;                 // 0..41
        const float* wo  = cw1 + o * 25;
        const float  bia = cb1[o];
#pragma unroll 1
        for (int jj = 0; jj < 4; ++jj) {
            int j = jj * 42 + li;
            if (j < 144) {
                int inst = j / 36, rem = j % 36;
                int py = rem / 3, g = rem % 3;
                const float* base = &s_img[inst * 784 + (py * 2) * 28 + g * 8];

                float accA[8], accB[8];
#pragma unroll
                for (int i = 0; i < 8; ++i) { accA[i] = 0.f; accB[i] = 0.f; }

                const float4* rp = (const float4*)base;
                float4 a0 = rp[0], a1 = rp[1], a2 = rp[2];
                float rC[12] = {a0.x,a0.y,a0.z,a0.w,a1.x,a1.y,a1.z,a1.w,a2.x,a2.y,a2.z,a2.w};
#pragma unroll
                for (int ky = 0; ky < 5; ++ky) {
                    float w5[5];
#pragma unroll
                    for (int kx = 0; kx < 5; ++kx) w5[kx] = wo[ky * 5 + kx];
                    const float4* np = (const float4*)(base + (ky + 1) * 28);
                    float4 b0v = np[0], b1v = np[1], b2v = np[2];
                    float rN[12] = {b0v.x,b0v.y,b0v.z,b0v.w,b1v.x,b1v.y,b1v.z,b1v.w,b2v.x,b2v.y,b2v.z,b2v.w};
#pragma unroll
                    for (int kx = 0; kx < 5; ++kx) {
                        float wv = w5[kx];
#pragma unroll
                        for (int c = 0; c < 8; ++c) {
                            accA[c] = fmaf(rC[c + kx], wv, accA[c]);
                            accB[c] = fmaf(rN[c + kx], wv, accB[c]);
                        }
                    }
#pragma unroll
                    for (int i = 0; i < 12; ++i) rC[i] = rN[i];
                }
                float4 res;
                res.x = fmaxf(fmaxf(fmaxf(accA[0], accA[1]), fmaxf(accB[0], accB[1])) + bia, 0.f);
                res.y = fmaxf(fmaxf(fmaxf(accA[2], accA[3]), fmaxf(accB[2], accB[3])) + bia, 0.f);
                res.z = fmaxf(fmaxf(fmaxf(accA[4], accA[5]), fmaxf(accB[4], accB[5])) + bia, 0.f);
                res.w = fmaxf(fmaxf(fmaxf(accA[6], accA[7]), fmaxf(accB[6], accB[7])) + bia, 0.f);
                *(float4*)&s_p1[inst * P1_IN + o * P1_IC + py * 12 + g * 4] = res;
            }
        }
    }
    __syncthreads();

    // ---- conv2 5x5 (6->16) + pool2x2 + relu : exactly 256 tasks, 1 round ----
    // lane = o(16) x [inst(4) + 4*py(4)] ; conflict-free s_p1 reads under
    // padded strides (inst: bank+24, py: bank+24, broadcast over o).
    {
        const int o    = tid & 15;
        const int u    = tid >> 4;
        const int inst = u & 3;
        const int py   = u >> 2;
        const float* wbase = cw2 + o * 150;
        const float  bia   = cb2[o];
        const float* pb    = &s_p1[inst * P1_IN + (py * 2) * 12];

        float accA[8], accB[8];
#pragma unroll
        for (int i = 0; i < 8; ++i) { accA[i] = 0.f; accB[i] = 0.f; }

#pragma unroll 1
        for (int ic = 0; ic < 6; ++ic) {
            const float* prow = pb + ic * P1_IC;
            const float* wic  = wbase + ic * 25;

            const float4* rp = (const float4*)prow;
            float4 a0 = rp[0], a1 = rp[1], a2 = rp[2];
            float rC[12] = {a0.x,a0.y,a0.z,a0.w,a1.x,a1.y,a1.z,a1.w,a2.x,a2.y,a2.z,a2.w};
#pragma unroll
            for (int ky = 0; ky < 5; ++ky) {
                float w5[5];
#pragma unroll
                for (int kx = 0; kx < 5; ++kx) w5[kx] = wic[ky * 5 + kx];
                const float4* np = (const float4*)(prow + (ky + 1) * 12);
                float4 b0v = np[0], b1v = np[1], b2v = np[2];
                float rN[12] = {b0v.x,b0v.y,b0v.z,b0v.w,b1v.x,b1v.y,b1v.z,b1v.w,b2v.x,b2v.y,b2v.z,b2v.w};
#pragma unroll
                for (int kx = 0; kx < 5; ++kx) {
                    float wv = w5[kx];
#pragma unroll
                    for (int c = 0; c < 8; ++c) {
                        accA[c] = fmaf(rC[c + kx], wv, accA[c]);
                        accB[c] = fmaf(rN[c + kx], wv, accB[c]);
                    }
                }
#pragma unroll
                for (int i = 0; i < 12; ++i) rC[i] = rN[i];
            }
        }
        float4 res;
        res.x = fmaxf(fmaxf(fmaxf(accA[0], accA[1]), fmaxf(accB[0], accB[1])) + bia, 0.f);
        res.y = fmaxf(fmaxf(fmaxf(accA[2], accA[3]), fmaxf(accB[2], accB[3])) + bia, 0.f);
        res.z = fmaxf(fmaxf(fmaxf(accA[4], accA[5]), fmaxf(accB[4], accB[5])) + bia, 0.f);
        res.w = fmaxf(fmaxf(fmaxf(accA[6], accA[7]), fmaxf(accB[6], accB[7])) + bia, 0.f);
        // wait for conv1 consumers done is implied by the barrier above;
        // s_p2 aliases s_img which is dead now.
        *(float4*)&s_p2[inst * 256 + o * 16 + py * 4] = res;
    }
    __syncthreads();

    // ---- fc1: 256 -> 120, relu. 240 lanes, 2 instances each ----
    if (tid < 240) {
        int o  = tid % 120;
        int pr = tid / 120;
        const float4* wr = (const float4*)(fw1 + o * 256);
        const float4* q0 = (const float4*)(s_p2 + (2 * pr    ) * 256);
        const float4* q1 = (const float4*)(s_p2 + (2 * pr + 1) * 256);
        float a0 = 0.f, a1 = 0.f;
#pragma unroll 4
        for (int k = 0; k < 64; ++k) {
            float4 w4 = wr[k];
            float4 p;
            p = q0[k]; a0 = fmaf(w4.x,p.x,a0); a0 = fmaf(w4.y,p.y,a0); a0 = fmaf(w4.z,p.z,a0); a0 = fmaf(w4.w,p.w,a0);
            p = q1[k]; a1 = fmaf(w4.x,p.x,a1); a1 = fmaf(w4.y,p.y,a1); a1 = fmaf(w4.z,p.z,a1); a1 = fmaf(w4.w,p.w,a1);
        }
        float bb = fb1[o];
        s_f1[(2 * pr    ) * 120 + o] = fmaxf(a0 + bb, 0.f);
        s_f1[(2 * pr + 1) * 120 + o] = fmaxf(a1 + bb, 0.f);
    }
    __syncthreads();

    // ---- fc2: 120 -> 84, relu. 168 lanes, 2 instances each ----
    if (tid < 168) {
        int o  = tid % 84;
        int pr = tid / 84;
        const float4* wr = (const float4*)(fw2 + o * 120);
        const float4* q0 = (const float4*)(s_f1 + (2 * pr    ) * 120);
        const float4* q1 = (const float4*)(s_f1 + (2 * pr + 1) * 120);
        float a0 = 0.f, a1 = 0.f;
#pragma unroll 5
        for (int k = 0; k < 30; ++k) {
            float4 w4 = wr[k];
            float4 p;
            p = q0[k]; a0 = fmaf(w4.x,p.x,a0); a0 = fmaf(w4.y,p.y,a0); a0 = fmaf(w4.z,p.z,a0); a0 = fmaf(w4.w,p.w,a0);
            p = q1[k]; a1 = fmaf(w4.x,p.x,a1); a1 = fmaf(w4.y,p.y,a1); a1 = fmaf(w4.z,p.z,a1); a1 = fmaf(w4.w,p.w,a1);
        }
        float bb = fb2[o];
        s_f2[(2 * pr    ) * 84 + o] = fmaxf(a0 + bb, 0.f);
        s_f2[(2 * pr + 1) * 84 + o] = fmaxf(a1 + bb, 0.f);
    }
    __syncthreads();

    // ---- fc3: 84 -> 10. 40 lanes ----
    if (tid < 40) {
        int o    = tid % 10;
        int inst = tid / 10;
        const float4* wr = (const float4*)(fw3 + o * 84);
        const float4* q0 = (const float4*)(s_f2 + inst * 84);
        float a0 = 0.f;
#pragma unroll
        for (int k = 0; k < 21; ++k) {
            float4 w4 = wr[k];
            float4 p = q0[k];
            a0 = fmaf(w4.x,p.x,a0); a0 = fmaf(w4.y,p.y,a0); a0 = fmaf(w4.z,p.z,a0); a0 = fmaf(w4.w,p.w,a0);
        }
        s_log[inst * 10 + o] = a0 + fb3[o];
    }
    __syncthreads();

    // ---- softmax (in-lane) + full convolution (len 19) + log ----
    if (tid < 19 * SPB) {
        int ls = tid / 19;
        int t  = tid % 19;
        const float* la = &s_log[(ls * 2 + 0) * 10];
        const float* lb = &s_log[(ls * 2 + 1) * 10];
        float pa[10], pb[10];
        float mxa = la[0], mxb = lb[0];
#pragma unroll
        for (int j = 1; j < 10; ++j) { mxa = fmaxf(mxa, la[j]); mxb = fmaxf(mxb, lb[j]); }
        float sa = 0.f, sb = 0.f;
#pragma unroll
        for (int j = 0; j < 10; ++j) {
            pa[j] = __expf(la[j] - mxa); sa += pa[j];
            pb[j] = __expf(lb[j] - mxb); sb += pb[j];
        }
        float inv = 1.f / (sa * sb);
        int jlo = t - 9 > 0 ? t - 9 : 0;
        int jhi = t < 9 ? t : 9;
        float z = 0.f;
        for (int j = jlo; j <= jhi; ++j)
            z += pa[j] * pb[t - j];
        out[(size_t)(b0 + ls) * 19 + t] = __logf(z * inv);
    }
}

extern "C" void kernel_launch(void* const* d_in, const int* in_sizes, int n_in,
                              void* d_out, int out_size, void* d_ws, size_t ws_size,
                              hipStream_t stream) {
    const float* x   = (const float*)d_in[0];
    const float* cw1 = (const float*)d_in[1];
    const float* cb1 = (const float*)d_in[2];
    const float* cw2 = (const float*)d_in[3];
    const float* cb2 = (const float*)d_in[4];
    const float* fw1 = (const float*)d_in[5];
    const float* fb1 = (const float*)d_in[6];
    const float* fw2 = (const float*)d_in[7];
    const float* fb2 = (const float*)d_in[8];
    const float* fw3 = (const float*)d_in[9];
    const float* fb3 = (const float*)d_in[10];
    float* out = (float*)d_out;

    const int B = in_sizes[0] / (2 * 28 * 28);   // 16384

    lenet_fused<<<B / SPB, 256, 0, stream>>>(x, cw1, cb1, cw2, cb2,
                                             fw1, fb1, fw2, fb2, fw3, fb3, out);
}